// Round 5
// baseline (503.592 us; speedup 1.0000x reference)
//
#include <hip/hip_runtime.h>

// Transformer-XL attention, MI355X gfx950.
// All tensors are fp32 in global memory (per reference). Internal GEMM path
// converts activations/weights to bf16 once, MFMA accumulates in fp32.
// B=4 TQ=1024 TK=1536 D=1024 H=16 DV=64, mem=512 causal: j <= i+512.

typedef unsigned short u16;
typedef __attribute__((ext_vector_type(8))) short short8;   // 8 bf16 = 4 VGPRs (MFMA A/B frag)
typedef __attribute__((ext_vector_type(4))) float floatx4;  // MFMA C/D frag

__device__ __forceinline__ float bf2f(u16 u) {
    union { unsigned int i; float f; } w; w.i = ((unsigned int)u) << 16; return w.f;
}
__device__ __forceinline__ u16 f2bf(float f) {
    union { unsigned int i; float f; } w; w.f = f;
    unsigned int u = w.i;
    return (u16)((u + 0x7FFFu + ((u >> 16) & 1u)) >> 16);
}
__device__ __forceinline__ u16 f2bf_trunc(float f) {  // 1-op truncating cvt
    union { unsigned int i; float f; } w; w.f = f;
    return (u16)(w.i >> 16);
}

// ---------------------------------------------------------------------------
// fp32 -> bf16 flat conversion (n divisible by 8)
// ---------------------------------------------------------------------------
__global__ __launch_bounds__(256) void cvt_kernel(
    const float* __restrict__ x, u16* __restrict__ y, int n)
{
    const int i = (blockIdx.x * 256 + threadIdx.x) * 8;
    if (i >= n) return;
    float4 a = *(const float4*)&x[i];
    float4 b = *(const float4*)&x[i + 4];
    short8 o;
    o[0] = (short)f2bf(a.x); o[1] = (short)f2bf(a.y);
    o[2] = (short)f2bf(a.z); o[3] = (short)f2bf(a.w);
    o[4] = (short)f2bf(b.x); o[5] = (short)f2bf(b.y);
    o[6] = (short)f2bf(b.z); o[7] = (short)f2bf(b.w);
    *(short8*)&y[i] = o;
}

// ---------------------------------------------------------------------------
// Weight transpose + cvt: WT[n][k] = bf16(W[k][n]).  W is 1024x1024 fp32.
// ---------------------------------------------------------------------------
__global__ __launch_bounds__(256) void transpose_kernel(
    const float* __restrict__ W, u16* __restrict__ WT, int dst_ld, int dst_koff)
{
    __shared__ u16 ts[64][72];
    const int k0 = blockIdx.x * 64, n0 = blockIdx.y * 64;
    const int r  = threadIdx.x >> 2;        // 0..63
    const int c4 = (threadIdx.x & 3) << 4;  // 0,16,32,48
    const float* src = &W[(size_t)(k0 + r) * 1024 + n0 + c4];
    for (int j = 0; j < 16; j += 4) {
        float4 a = *(const float4*)(src + j);
        ts[r][c4 + j + 0] = f2bf(a.x);
        ts[r][c4 + j + 1] = f2bf(a.y);
        ts[r][c4 + j + 2] = f2bf(a.z);
        ts[r][c4 + j + 3] = f2bf(a.w);
    }
    __syncthreads();
    short8 t0, t1;
    for (int j = 0; j < 8; j++) t0[j] = (short)ts[c4 + j][r];
    for (int j = 0; j < 8; j++) t1[j] = (short)ts[c4 + 8 + j][r];
    u16* dst = &WT[(size_t)(n0 + r) * dst_ld + dst_koff + k0 + c4];
    *(short8*)dst       = t0;
    *(short8*)(dst + 8) = t1;
}

// ---------------------------------------------------------------------------
// wuvb[h][k] (bf16, [16][2048]): k<1024 -> sum_d Wk[k][h*64+d]*u[d]
//                                k>=1024 -> sum_d Wr[k-1024][h*64+d]*v[d]
// ---------------------------------------------------------------------------
__global__ __launch_bounds__(256) void wuv_kernel(
    const float* __restrict__ Wk, const float* __restrict__ Wr,
    const float* __restrict__ u, const float* __restrict__ v,
    u16* __restrict__ wuvb)
{
    int idx = blockIdx.x * 256 + threadIdx.x;  // 16384 threads
    int c = idx >> 4, h = idx & 15;
    float au = 0.f, av = 0.f;
    for (int d = 0; d < 64; d++) {
        au += Wk[(size_t)c * 1024 + h * 64 + d] * u[d];
        av += Wr[(size_t)c * 1024 + h * 64 + d] * v[d];
    }
    wuvb[h * 2048 + c]        = f2bf(au);
    wuvb[h * 2048 + 1024 + c] = f2bf(av);
}

// ---------------------------------------------------------------------------
// bias[b][h][t] = kv[b,t,:]·wu[h,:] + rel[b,t,:]·wv[h,:] as a skinny MFMA GEMM:
// [6144 tokens, 2048] @ [2048, 16 heads]. One wave per 16 tokens, 4 waves/block.
// ---------------------------------------------------------------------------
__global__ __launch_bounds__(256) void bias_kernel(
    const u16* __restrict__ kvb, const u16* __restrict__ relb,
    const u16* __restrict__ wuvb, float* __restrict__ bias)
{
    const int tid = threadIdx.x;
    const int wave = tid >> 6, lane = tid & 63;
    const int l16 = lane & 15, quad = lane >> 4;
    const int tBase = blockIdx.x * 64 + wave * 16;  // 96 blocks * 64 tokens

    floatx4 acc = {0.f, 0.f, 0.f, 0.f};
    const u16* arow_kv  = kvb  + (size_t)(tBase + l16) * 1024;
    const u16* arow_rel = relb + (size_t)(tBase + l16) * 1024;
    const u16* brow     = wuvb + (size_t)l16 * 2048;

    for (int ks = 0; ks < 64; ks++) {
        const int k0 = ks * 32;
        const u16* ap = (k0 < 1024) ? (arow_kv + k0) : (arow_rel + k0 - 1024);
        short8 af = *(const short8*)(ap + quad * 8);
        short8 bf = *(const short8*)(brow + k0 + quad * 8);
        acc = __builtin_amdgcn_mfma_f32_16x16x32_bf16(af, bf, acc, 0, 0, 0);
    }
    for (int rg = 0; rg < 4; rg++) {
        const int tg = tBase + quad * 4 + rg;
        const int b = tg / 1536, t = tg % 1536;
        bias[((size_t)b * 16 + l16) * 1536 + t] = acc[rg];
    }
}

// ---------------------------------------------------------------------------
// Generic GEMM: C[M][1024] = A[M][Ktot] @ W, W given transposed WT[1024][Ktot].
// EPI 0: bf16 head-layout out[((b*16+h)*T + t)*64 + d]
// EPI 1: fp32 token-layout + fp32 residual add
// EPI 2: bf16 head-TRANSPOSED layout out[((b*16+h)*64 + d)*1536 + t]  (V^T)
// ---------------------------------------------------------------------------
template <int EPI>
__global__ __launch_bounds__(256) void gemm_proj(
    const u16* __restrict__ A0, const u16* __restrict__ A1,
    const u16* __restrict__ WT, void* __restrict__ out,
    const float* __restrict__ resid, int Ktot, int Ksplit, int T)
{
    const int bm = blockIdx.x, bn = blockIdx.y;
    const int tid = threadIdx.x;
    const int wave = tid >> 6, lane = tid & 63;
    const int wm = wave >> 1, wn = wave & 1;
    const int l16 = lane & 15, quad = lane >> 4;

    __shared__ u16 As[128][40];
    __shared__ u16 Ws[128][40];

    floatx4 acc[4][4];
    const floatx4 zf = {0.f, 0.f, 0.f, 0.f};
    for (int i = 0; i < 4; i++) for (int j = 0; j < 4; j++) acc[i][j] = zf;

    const int r  = tid >> 1;         // staging row 0..127
    const int c0 = (tid & 1) << 4;   // 0 or 16
    const int m_base = bm * 128, n_base = bn * 128;

    for (int k0 = 0; k0 < Ktot; k0 += 32) {
        const u16* Aptr; int kk;
        if (k0 < Ksplit) { Aptr = A0; kk = k0; } else { Aptr = A1; kk = k0 - Ksplit; }
        __syncthreads();
        {
            const u16* src = Aptr + (size_t)(m_base + r) * 1024 + kk + c0;
            short8 a0 = *(const short8*)src;
            short8 a1 = *(const short8*)(src + 8);
            *(short8*)&As[r][c0]     = a0;
            *(short8*)&As[r][c0 + 8] = a1;
            const u16* wsrc = WT + (size_t)(n_base + r) * Ktot + k0 + c0;
            short8 b0 = *(const short8*)wsrc;
            short8 b1 = *(const short8*)(wsrc + 8);
            *(short8*)&Ws[r][c0]     = b0;
            *(short8*)&Ws[r][c0 + 8] = b1;
        }
        __syncthreads();
        short8 af[4], bf[4];
        for (int i = 0; i < 4; i++) {
            af[i] = *(const short8*)&As[wm * 64 + i * 16 + l16][quad * 8];
            bf[i] = *(const short8*)&Ws[wn * 64 + i * 16 + l16][quad * 8];
        }
        for (int i = 0; i < 4; i++)
            for (int j = 0; j < 4; j++)
                acc[i][j] = __builtin_amdgcn_mfma_f32_16x16x32_bf16(af[i], bf[j], acc[i][j], 0, 0, 0);
    }

    for (int i = 0; i < 4; i++) {
        for (int rg = 0; rg < 4; rg++) {
            const int m = m_base + wm * 64 + i * 16 + quad * 4 + rg;
            if (EPI == 0) {
                const int b = m / T, t = m % T;
                u16* op = (u16*)out;
                for (int j = 0; j < 4; j++) {
                    const int col = n_base + wn * 64 + j * 16 + l16;
                    const int h = col >> 6, d = col & 63;
                    op[((((size_t)b * 16 + h) * T + t) << 6) + d] = f2bf(acc[i][j][rg]);
                }
            } else if (EPI == 2) {
                const int b = m / T, t = m % T;
                u16* op = (u16*)out;
                for (int j = 0; j < 4; j++) {
                    const int col = n_base + wn * 64 + j * 16 + l16;
                    const int h = col >> 6, d = col & 63;
                    op[(((size_t)b * 16 + h) * 64 + d) * 1536 + t] = f2bf(acc[i][j][rg]);
                }
            } else {
                float* op = (float*)out;
                for (int j = 0; j < 4; j++) {
                    const int col = n_base + wn * 64 + j * 16 + l16;
                    op[(size_t)m * 1024 + col] =
                        acc[i][j][rg] + resid[(size_t)m * 1024 + col];
                }
            }
        }
    }
}

// ---------------------------------------------------------------------------
// Flash attention v3: logits = (Q·KR)*0.125 + bias[j]*0.125, causal j<=i+512.
// Exact softmax without running max (logit range ~±4, no overflow).
// No barriers; V pre-transposed; P through per-wave LDS.
// 1024 blocks, 64 q/block, 16 q/wave: 4 blocks/CU, 16 waves/CU for TLP
// (round-4 postmortem: 1.3 waves/SIMD was the latency-bound killer).
// blk&63 = (b,h): one head's 16 q-blocks share an XCD residue (L2 reuse).
// __launch_bounds__(256,4): cap VGPR at 128 so 4 waves/SIMD fit.
// ---------------------------------------------------------------------------
__global__ __launch_bounds__(256, 4) void attn_kernel(
    const u16* __restrict__ Qh,   // [B][H][1024][64]
    const u16* __restrict__ KRh,  // [B][H][1536][64]
    const u16* __restrict__ Vt,   // [B][H][64][1536]  (transposed V)
    const float* __restrict__ bias, // [B][H][1536]
    u16* __restrict__ ctx)        // [B][1024][1024] token-major
{
    const int blk  = blockIdx.x;       // 0..1023
    const int hb   = blk & 63;         // (b,h)
    const int qsub = blk >> 6;         // 0..15
    const int b = hb >> 4, h = hb & 15;
    const int tid = threadIdx.x;
    const int wave = tid >> 6, lane = tid & 63;
    const int l16 = lane & 15, quad = lane >> 4;
    const int q0 = qsub * 64;
    const int qw = q0 + wave * 16;

    const u16* Qp = Qh  + (size_t)hb * 1024 * 64;
    const u16* Kp = KRh + (size_t)hb * 1536 * 64;
    const u16* Vp = Vt  + (size_t)hb * 64 * 1536;
    const float* bp = bias + (size_t)hb * 1536;

    __shared__ u16 Ps[4][16][68];  // per-wave P staging (8.5 KB)

    short8 aq[2];
    for (int ks = 0; ks < 2; ks++)
        aq[ks] = *(const short8*)&Qp[(size_t)(qw + l16) * 64 + ks * 32 + quad * 8];

    const floatx4 zf = {0.f, 0.f, 0.f, 0.f};
    floatx4 accO[4];
    float lsum[4];
    for (int j = 0; j < 4; j++) accO[j] = zf;
    for (int rg = 0; rg < 4; rg++) lsum[rg] = 0.f;

    const int nkt = qsub + 9;  // ceil((q0+63+512+1)/64)
    for (int kt = 0; kt < nkt; kt++) {
        const int k0 = kt * 64;

        short8 bk[4][2], bv[4][2];
        float bcol[4];
        for (int n = 0; n < 4; n++)
            for (int ks = 0; ks < 2; ks++)
                bk[n][ks] = *(const short8*)
                    &Kp[(size_t)(k0 + n * 16 + l16) * 64 + ks * 32 + quad * 8];
        for (int j = 0; j < 4; j++)
            for (int ks = 0; ks < 2; ks++)
                bv[j][ks] = *(const short8*)
                    &Vp[(size_t)(j * 16 + l16) * 1536 + k0 + ks * 32 + quad * 8];
        for (int n = 0; n < 4; n++) bcol[n] = bp[k0 + n * 16 + l16] * 0.125f;

        floatx4 accS[4];
        for (int n = 0; n < 4; n++) {
            accS[n] = zf;
            for (int ks = 0; ks < 2; ks++)
                accS[n] = __builtin_amdgcn_mfma_f32_16x16x32_bf16(
                    aq[ks], bk[n][ks], accS[n], 0, 0, 0);
        }

        const int qrow = qw + quad * 4;  // + rg
        const bool domask = (k0 + 63 > qw + 15 + 512);  // wave-uniform
        for (int n = 0; n < 4; n++) {
            const int col = k0 + n * 16 + l16;
            for (int rg = 0; rg < 4; rg++) {
                float p = __expf(fmaf(accS[n][rg], 0.125f, bcol[n]));
                if (domask && col > qrow + rg + 512) p = 0.f;
                lsum[rg] += p;
                Ps[wave][quad * 4 + rg][n * 16 + l16] = f2bf_trunc(p);
            }
        }

        // wave-local LDS round trip (compiler inserts lgkmcnt wait; no barrier)
        short8 ap[2];
        for (int ks = 0; ks < 2; ks++)
            ap[ks] = *(const short8*)&Ps[wave][l16][ks * 32 + quad * 8];
        for (int j = 0; j < 4; j++)
            for (int ks = 0; ks < 2; ks++)
                accO[j] = __builtin_amdgcn_mfma_f32_16x16x32_bf16(
                    ap[ks], bv[j][ks], accO[j], 0, 0, 0);
    }

    for (int rg = 0; rg < 4; rg++) {
        float s = lsum[rg];
        for (int off = 1; off < 16; off <<= 1) s += __shfl_xor(s, off, 64);
        lsum[rg] = s;
    }

    for (int j = 0; j < 4; j++)
        for (int rg = 0; rg < 4; rg++) {
            const int q = qw + quad * 4 + rg;
            const int d = j * 16 + l16;
            ctx[((size_t)b * 1024 + q) * 1024 + h * 64 + d] =
                f2bf(accO[j][rg] / lsum[rg]);
        }
}

// ---------------------------------------------------------------------------
// LayerNorm: one block per row of 1024, fp32 in -> fp32 out
// ---------------------------------------------------------------------------
__global__ __launch_bounds__(256) void ln_kernel(
    const float* __restrict__ x, const float* __restrict__ gamma,
    const float* __restrict__ beta, float* __restrict__ out)
{
    const int row = blockIdx.x;
    const int tid = threadIdx.x;
    const float* xp = x + (size_t)row * 1024;
    float4 v = *(const float4*)&xp[tid * 4];
    float s  = v.x + v.y + v.z + v.w;
    float ss = v.x * v.x + v.y * v.y + v.z * v.z + v.w * v.w;
    for (int off = 1; off < 64; off <<= 1) {
        s  += __shfl_xor(s, off, 64);
        ss += __shfl_xor(ss, off, 64);
    }
    __shared__ float sm[8];
    const int wave = tid >> 6, lane = tid & 63;
    if (lane == 0) { sm[wave] = s; sm[4 + wave] = ss; }
    __syncthreads();
    s  = sm[0] + sm[1] + sm[2] + sm[3];
    ss = sm[4] + sm[5] + sm[6] + sm[7];
    const float mu  = s * (1.f / 1024.f);
    const float var = ss * (1.f / 1024.f) - mu * mu;
    const float inv = rsqrtf(var + 1e-5f);
    float* op = out + (size_t)row * 1024;
    const float* ve = &v.x;
    for (int j = 0; j < 4; j++) {
        const int c = tid * 4 + j;
        op[c] = (ve[j] - mu) * inv * gamma[c] + beta[c];
    }
}

// ---------------------------------------------------------------------------
extern "C" void kernel_launch(void* const* d_in, const int* in_sizes, int n_in,
                              void* d_out, int out_size, void* d_ws, size_t ws_size,
                              hipStream_t stream)
{
    const float* query     = (const float*)d_in[0];
    const float* key_value = (const float*)d_in[1];
    const float* relative  = (const float*)d_in[2];
    // d_in[3] = mask: analytic (j <= i+512), unused
    const float* Wq = (const float*)d_in[4];
    const float* Wk = (const float*)d_in[5];
    const float* Wv = (const float*)d_in[6];
    const float* Wr = (const float*)d_in[7];
    const float* Wo = (const float*)d_in[8];
    const float* u  = (const float*)d_in[9];
    const float* v  = (const float*)d_in[10];
    const float* gamma = (const float*)d_in[11];
    const float* beta  = (const float*)d_in[12];

    char* wsp = (char*)d_ws;
    auto alloc = [&](size_t bytes) -> char* {
        char* p = wsp; wsp += (bytes + 255) & ~(size_t)255; return p;
    };
    u16*   qb   = (u16*)alloc((size_t)4 * 1024 * 1024 * 2);      // bf16 query
    u16*   kvb  = (u16*)alloc((size_t)4 * 1536 * 1024 * 2);      // bf16 key_value
    u16*   relb = (u16*)alloc((size_t)4 * 1536 * 1024 * 2);      // bf16 relative
    u16*   WqT  = (u16*)alloc((size_t)1024 * 1024 * 2);
    u16*   WkrT = (u16*)alloc((size_t)1024 * 2048 * 2);
    u16*   WvT  = (u16*)alloc((size_t)1024 * 1024 * 2);
    u16*   WoT  = (u16*)alloc((size_t)1024 * 1024 * 2);
    u16*   wuvb = (u16*)alloc((size_t)16 * 2048 * 2);            // bf16 [16][2048]
    u16*   Qh   = (u16*)alloc((size_t)4 * 16 * 1024 * 64 * 2);
    u16*   KRh  = (u16*)alloc((size_t)4 * 16 * 1536 * 64 * 2);
    u16*   Vt   = (u16*)alloc((size_t)4 * 16 * 64 * 1536 * 2);   // transposed V
    float* bias = (float*)alloc((size_t)4 * 16 * 1536 * 4);
    u16*   ctx  = (u16*)alloc((size_t)4 * 1024 * 1024 * 2);
    float* outp = (float*)alloc((size_t)4 * 1024 * 1024 * 4);

    const dim3 tb(256);
    cvt_kernel<<<dim3(4 * 1024 * 1024 / 8 / 256), tb, 0, stream>>>(query, qb, 4 * 1024 * 1024);
    cvt_kernel<<<dim3(4 * 1536 * 1024 / 8 / 256), tb, 0, stream>>>(key_value, kvb, 4 * 1536 * 1024);
    cvt_kernel<<<dim3(4 * 1536 * 1024 / 8 / 256), tb, 0, stream>>>(relative, relb, 4 * 1536 * 1024);

    transpose_kernel<<<dim3(16, 16), tb, 0, stream>>>(Wq, WqT, 1024, 0);
    transpose_kernel<<<dim3(16, 16), tb, 0, stream>>>(Wk, WkrT, 2048, 0);
    transpose_kernel<<<dim3(16, 16), tb, 0, stream>>>(Wr, WkrT, 2048, 1024);
    transpose_kernel<<<dim3(16, 16), tb, 0, stream>>>(Wv, WvT, 1024, 0);
    transpose_kernel<<<dim3(16, 16), tb, 0, stream>>>(Wo, WoT, 1024, 0);
    wuv_kernel<<<64, tb, 0, stream>>>(Wk, Wr, u, v, wuvb);

    gemm_proj<0><<<dim3(32, 8), tb, 0, stream>>>(qb, nullptr, WqT, Qh, nullptr, 1024, 1024, 1024);
    gemm_proj<0><<<dim3(48, 8), tb, 0, stream>>>(kvb, relb, WkrT, KRh, nullptr, 2048, 1024, 1536);
    gemm_proj<2><<<dim3(48, 8), tb, 0, stream>>>(kvb, nullptr, WvT, Vt, nullptr, 1024, 1024, 1536);
    bias_kernel<<<dim3(96), tb, 0, stream>>>(kvb, relb, wuvb, bias);

    attn_kernel<<<dim3(1024), tb, 0, stream>>>(Qh, KRh, Vt, bias, ctx);

    gemm_proj<1><<<dim3(32, 8), tb, 0, stream>>>(ctx, nullptr, WoT, outp, query, 1024, 1024, 1024);
    ln_kernel<<<4096, tb, 0, stream>>>(outp, gamma, beta, (float*)d_out);
}

// Round 6
// 433.076 us; speedup vs baseline: 1.1628x; 1.1628x over previous
//
#include <hip/hip_runtime.h>

// Transformer-XL attention, MI355X gfx950.
// All tensors are fp32 in global memory (per reference). Internal GEMM path
// converts activations/weights to bf16 once, MFMA accumulates in fp32.
// B=4 TQ=1024 TK=1536 D=1024 H=16 DV=64, mem=512 causal: j <= i+512.

typedef unsigned short u16;
typedef __attribute__((ext_vector_type(8))) short short8;   // 8 bf16 = 4 VGPRs (MFMA A/B frag)
typedef __attribute__((ext_vector_type(4))) float floatx4;  // MFMA C/D frag

__device__ __forceinline__ float bf2f(u16 u) {
    union { unsigned int i; float f; } w; w.i = ((unsigned int)u) << 16; return w.f;
}
__device__ __forceinline__ u16 f2bf(float f) {
    union { unsigned int i; float f; } w; w.f = f;
    unsigned int u = w.i;
    return (u16)((u + 0x7FFFu + ((u >> 16) & 1u)) >> 16);
}

// async global->LDS, 16B per lane; LDS dest = wave-uniform base + lane*16
__device__ __forceinline__ void gl_lds16(const u16* g, u16* lds) {
    __builtin_amdgcn_global_load_lds(
        (const __attribute__((address_space(1))) void*)g,
        (__attribute__((address_space(3))) void*)lds, 16, 0, 0);
}

// ---------------------------------------------------------------------------
// fp32 -> bf16 flat conversion (n divisible by 8)
// ---------------------------------------------------------------------------
__global__ __launch_bounds__(256) void cvt_kernel(
    const float* __restrict__ x, u16* __restrict__ y, int n)
{
    const int i = (blockIdx.x * 256 + threadIdx.x) * 8;
    if (i >= n) return;
    float4 a = *(const float4*)&x[i];
    float4 b = *(const float4*)&x[i + 4];
    short8 o;
    o[0] = (short)f2bf(a.x); o[1] = (short)f2bf(a.y);
    o[2] = (short)f2bf(a.z); o[3] = (short)f2bf(a.w);
    o[4] = (short)f2bf(b.x); o[5] = (short)f2bf(b.y);
    o[6] = (short)f2bf(b.z); o[7] = (short)f2bf(b.w);
    *(short8*)&y[i] = o;
}

// ---------------------------------------------------------------------------
// Weight transpose + cvt: WT[n][k] = bf16(W[k][n]).  W is 1024x1024 fp32.
// ---------------------------------------------------------------------------
__global__ __launch_bounds__(256) void transpose_kernel(
    const float* __restrict__ W, u16* __restrict__ WT, int dst_ld, int dst_koff)
{
    __shared__ u16 ts[64][72];
    const int k0 = blockIdx.x * 64, n0 = blockIdx.y * 64;
    const int r  = threadIdx.x >> 2;        // 0..63
    const int c4 = (threadIdx.x & 3) << 4;  // 0,16,32,48
    const float* src = &W[(size_t)(k0 + r) * 1024 + n0 + c4];
    for (int j = 0; j < 16; j += 4) {
        float4 a = *(const float4*)(src + j);
        ts[r][c4 + j + 0] = f2bf(a.x);
        ts[r][c4 + j + 1] = f2bf(a.y);
        ts[r][c4 + j + 2] = f2bf(a.z);
        ts[r][c4 + j + 3] = f2bf(a.w);
    }
    __syncthreads();
    short8 t0, t1;
    for (int j = 0; j < 8; j++) t0[j] = (short)ts[c4 + j][r];
    for (int j = 0; j < 8; j++) t1[j] = (short)ts[c4 + 8 + j][r];
    u16* dst = &WT[(size_t)(n0 + r) * dst_ld + dst_koff + k0 + c4];
    *(short8*)dst       = t0;
    *(short8*)(dst + 8) = t1;
}

// ---------------------------------------------------------------------------
// wuvb[h][k] (bf16, [16][2048]): k<1024 -> sum_d Wk[k][h*64+d]*u[d]
//                                k>=1024 -> sum_d Wr[k-1024][h*64+d]*v[d]
// ---------------------------------------------------------------------------
__global__ __launch_bounds__(256) void wuv_kernel(
    const float* __restrict__ Wk, const float* __restrict__ Wr,
    const float* __restrict__ u, const float* __restrict__ v,
    u16* __restrict__ wuvb)
{
    int idx = blockIdx.x * 256 + threadIdx.x;  // 16384 threads
    int c = idx >> 4, h = idx & 15;
    float au = 0.f, av = 0.f;
    for (int d = 0; d < 64; d++) {
        au += Wk[(size_t)c * 1024 + h * 64 + d] * u[d];
        av += Wr[(size_t)c * 1024 + h * 64 + d] * v[d];
    }
    wuvb[h * 2048 + c]        = f2bf(au);
    wuvb[h * 2048 + 1024 + c] = f2bf(av);
}

// ---------------------------------------------------------------------------
// bias[b][h][t] = kv[b,t,:]·wu[h,:] + rel[b,t,:]·wv[h,:] as a skinny MFMA GEMM:
// [6144 tokens, 2048] @ [2048, 16 heads]. One wave per 16 tokens, 4 waves/block.
// ---------------------------------------------------------------------------
__global__ __launch_bounds__(256) void bias_kernel(
    const u16* __restrict__ kvb, const u16* __restrict__ relb,
    const u16* __restrict__ wuvb, float* __restrict__ bias)
{
    const int tid = threadIdx.x;
    const int wave = tid >> 6, lane = tid & 63;
    const int l16 = lane & 15, quad = lane >> 4;
    const int tBase = blockIdx.x * 64 + wave * 16;  // 96 blocks * 64 tokens

    floatx4 acc = {0.f, 0.f, 0.f, 0.f};
    const u16* arow_kv  = kvb  + (size_t)(tBase + l16) * 1024;
    const u16* arow_rel = relb + (size_t)(tBase + l16) * 1024;
    const u16* brow     = wuvb + (size_t)l16 * 2048;

    for (int ks = 0; ks < 64; ks++) {
        const int k0 = ks * 32;
        const u16* ap = (k0 < 1024) ? (arow_kv + k0) : (arow_rel + k0 - 1024);
        short8 af = *(const short8*)(ap + quad * 8);
        short8 bf = *(const short8*)(brow + k0 + quad * 8);
        acc = __builtin_amdgcn_mfma_f32_16x16x32_bf16(af, bf, acc, 0, 0, 0);
    }
    for (int rg = 0; rg < 4; rg++) {
        const int tg = tBase + quad * 4 + rg;
        const int b = tg / 1536, t = tg % 1536;
        bias[((size_t)b * 16 + l16) * 1536 + t] = acc[rg];
    }
}

// ---------------------------------------------------------------------------
// Generic GEMM, m97-style: C[M][1024] = A[M][Ktot] @ W (WT[1024][Ktot]).
// global_load_lds width=16 staging into UNPADDED [128][32] LDS tiles
// (wave-uniform base + lane*16 layout constraint). 128x128 tile, 4 waves.
// EPI 0: bf16 head-layout out[((b*16+h)*T + t)*64 + d]
// EPI 1: fp32 token-layout + fp32 residual add
// EPI 2: bf16 head-TRANSPOSED layout out[((b*16+h)*64 + d)*1536 + t]  (V^T)
// ---------------------------------------------------------------------------
template <int EPI>
__global__ __launch_bounds__(256) void gemm_proj(
    const u16* __restrict__ A0, const u16* __restrict__ A1,
    const u16* __restrict__ WT, void* __restrict__ out,
    const float* __restrict__ resid, int Ktot, int Ksplit, int T)
{
    const int bm = blockIdx.x, bn = blockIdx.y;
    const int tid = threadIdx.x;
    const int wave = tid >> 6, lane = tid & 63;
    const int wm = wave >> 1, wn = wave & 1;
    const int l16 = lane & 15, quad = lane >> 4;

    __shared__ u16 As[128 * 32];  // unpadded: row r at As+r*32 (64B rows)
    __shared__ u16 Ws[128 * 32];

    floatx4 acc[4][4];
    const floatx4 zf = {0.f, 0.f, 0.f, 0.f};
    for (int i = 0; i < 4; i++) for (int j = 0; j < 4; j++) acc[i][j] = zf;

    const int m_base = bm * 128, n_base = bn * 128;
    const int rl = lane >> 2;          // 0..15 row within 16-row DMA group
    const int cl = (lane & 3) * 8;     // 0,8,16,24 col elems (16B)

    for (int k0 = 0; k0 < Ktot; k0 += 32) {
        const u16* Aptr; int kk;
        if (k0 < Ksplit) { Aptr = A0; kk = k0; } else { Aptr = A1; kk = k0 - Ksplit; }
        __syncthreads();  // all waves done reading prev-iter LDS
        for (int half = 0; half < 2; half++) {
            const int r = wave * 32 + half * 16;  // wave-uniform LDS base row
            gl_lds16(Aptr + (size_t)(m_base + r + rl) * 1024 + kk + cl, &As[r * 32]);
            gl_lds16(WT   + (size_t)(n_base + r + rl) * Ktot + k0 + cl, &Ws[r * 32]);
        }
        __syncthreads();  // vmcnt(0) drain: DMA data visible

        short8 af[4], bf[4];
        for (int i = 0; i < 4; i++) {
            af[i] = *(const short8*)&As[(wm * 64 + i * 16 + l16) * 32 + quad * 8];
            bf[i] = *(const short8*)&Ws[(wn * 64 + i * 16 + l16) * 32 + quad * 8];
        }
        for (int i = 0; i < 4; i++)
            for (int j = 0; j < 4; j++)
                acc[i][j] = __builtin_amdgcn_mfma_f32_16x16x32_bf16(af[i], bf[j], acc[i][j], 0, 0, 0);
    }

    for (int i = 0; i < 4; i++) {
        for (int rg = 0; rg < 4; rg++) {
            const int m = m_base + wm * 64 + i * 16 + quad * 4 + rg;
            if (EPI == 0) {
                const int b = m / T, t = m % T;
                u16* op = (u16*)out;
                for (int j = 0; j < 4; j++) {
                    const int col = n_base + wn * 64 + j * 16 + l16;
                    const int h = col >> 6, d = col & 63;
                    op[((((size_t)b * 16 + h) * T + t) << 6) + d] = f2bf(acc[i][j][rg]);
                }
            } else if (EPI == 2) {
                const int b = m / T, t = m % T;
                u16* op = (u16*)out;
                for (int j = 0; j < 4; j++) {
                    const int col = n_base + wn * 64 + j * 16 + l16;
                    const int h = col >> 6, d = col & 63;
                    op[(((size_t)b * 16 + h) * 64 + d) * 1536 + t] = f2bf(acc[i][j][rg]);
                }
            } else {
                float* op = (float*)out;
                for (int j = 0; j < 4; j++) {
                    const int col = n_base + wn * 64 + j * 16 + l16;
                    op[(size_t)m * 1024 + col] =
                        acc[i][j][rg] + resid[(size_t)m * 1024 + col];
                }
            }
        }
    }
}

// ---------------------------------------------------------------------------
// Flash attention (round-4 version, 83.8 µs — round-5 TLP experiment reverted:
// launch_bounds reg-cap demoted the 16 staged b128 loads, serializing L2
// latency; per-wave ILP beats waves/SIMD here).
// logits = (Q·KR + bias[j]) * 0.125, causal j <= i+512. Exact softmax without
// running max. No barriers; V pre-transposed; P via per-wave LDS.
// 512 blocks: blk&63 = (b,h) XCD-residue swizzle; 32 q/wave, 128 q/block.
// ---------------------------------------------------------------------------
__global__ __launch_bounds__(256) void attn_kernel(
    const u16* __restrict__ Qh,   // [B][H][1024][64]
    const u16* __restrict__ KRh,  // [B][H][1536][64]
    const u16* __restrict__ Vt,   // [B][H][64][1536]  (transposed V)
    const float* __restrict__ bias, // [B][H][1536]
    u16* __restrict__ ctx)        // [B][1024][1024] token-major
{
    const int blk  = blockIdx.x;       // 0..511
    const int hb   = blk & 63;         // (b,h)
    const int qblk = blk >> 6;         // 0..7
    const int b = hb >> 4, h = hb & 15;
    const int tid = threadIdx.x;
    const int wave = tid >> 6, lane = tid & 63;
    const int l16 = lane & 15, quad = lane >> 4;
    const int q0 = qblk * 128;

    const u16* Qp = Qh  + (size_t)hb * 1024 * 64;
    const u16* Kp = KRh + (size_t)hb * 1536 * 64;
    const u16* Vp = Vt  + (size_t)hb * 64 * 1536;
    const float* bp = bias + (size_t)hb * 1536;

    __shared__ u16 Ps[4][2][16][68];

    short8 aq[2][2];
    for (int mi = 0; mi < 2; mi++)
        for (int ks = 0; ks < 2; ks++)
            aq[mi][ks] = *(const short8*)
                &Qp[(size_t)(q0 + wave * 32 + mi * 16 + l16) * 64 + ks * 32 + quad * 8];

    const floatx4 zf = {0.f, 0.f, 0.f, 0.f};
    floatx4 accO[2][4];
    float lsum[2][4];
    for (int mi = 0; mi < 2; mi++)
        for (int j = 0; j < 4; j++) accO[mi][j] = zf;
    for (int mi = 0; mi < 2; mi++)
        for (int rg = 0; rg < 4; rg++) lsum[mi][rg] = 0.f;

    const int nkt = 2 * qblk + 10;  // causal reach
    for (int kt = 0; kt < nkt; kt++) {
        const int k0 = kt * 64;

        short8 bk[4][2], bv[4][2];
        float bcol[4];
        for (int n = 0; n < 4; n++)
            for (int ks = 0; ks < 2; ks++)
                bk[n][ks] = *(const short8*)
                    &Kp[(size_t)(k0 + n * 16 + l16) * 64 + ks * 32 + quad * 8];
        for (int j = 0; j < 4; j++)
            for (int ks = 0; ks < 2; ks++)
                bv[j][ks] = *(const short8*)
                    &Vp[(size_t)(j * 16 + l16) * 1536 + k0 + ks * 32 + quad * 8];
        for (int n = 0; n < 4; n++) bcol[n] = bp[k0 + n * 16 + l16];

        const bool domask = (k0 + 63 > q0 + 512);  // block-uniform branch

        for (int mi = 0; mi < 2; mi++) {
            floatx4 accS[4];
            for (int n = 0; n < 4; n++) {
                accS[n] = zf;
                for (int ks = 0; ks < 2; ks++)
                    accS[n] = __builtin_amdgcn_mfma_f32_16x16x32_bf16(
                        aq[mi][ks], bk[n][ks], accS[n], 0, 0, 0);
            }
            const int qrow = q0 + wave * 32 + mi * 16 + quad * 4;  // + rg
            for (int n = 0; n < 4; n++) {
                const int col = k0 + n * 16 + l16;
                for (int rg = 0; rg < 4; rg++) {
                    float s = (accS[n][rg] + bcol[n]) * 0.125f;
                    if (domask && col > qrow + rg + 512) s = -1e30f;
                    const float p = __expf(s);
                    lsum[mi][rg] += p;
                    Ps[wave][mi][quad * 4 + rg][n * 16 + l16] = f2bf(p);
                }
            }
            short8 ap[2];
            for (int ks = 0; ks < 2; ks++)
                ap[ks] = *(const short8*)&Ps[wave][mi][l16][ks * 32 + quad * 8];
            for (int j = 0; j < 4; j++)
                for (int ks = 0; ks < 2; ks++)
                    accO[mi][j] = __builtin_amdgcn_mfma_f32_16x16x32_bf16(
                        ap[ks], bv[j][ks], accO[mi][j], 0, 0, 0);
        }
    }

    for (int mi = 0; mi < 2; mi++)
        for (int rg = 0; rg < 4; rg++) {
            float s = lsum[mi][rg];
            for (int off = 1; off < 16; off <<= 1) s += __shfl_xor(s, off, 64);
            lsum[mi][rg] = s;
        }

    for (int mi = 0; mi < 2; mi++)
        for (int j = 0; j < 4; j++)
            for (int rg = 0; rg < 4; rg++) {
                const int q = q0 + wave * 32 + mi * 16 + quad * 4 + rg;
                const int d = j * 16 + l16;
                ctx[((size_t)b * 1024 + q) * 1024 + h * 64 + d] =
                    f2bf(accO[mi][j][rg] / lsum[mi][rg]);
            }
}

// ---------------------------------------------------------------------------
// LayerNorm: one block per row of 1024, fp32 in -> fp32 out
// ---------------------------------------------------------------------------
__global__ __launch_bounds__(256) void ln_kernel(
    const float* __restrict__ x, const float* __restrict__ gamma,
    const float* __restrict__ beta, float* __restrict__ out)
{
    const int row = blockIdx.x;
    const int tid = threadIdx.x;
    const float* xp = x + (size_t)row * 1024;
    float4 v = *(const float4*)&xp[tid * 4];
    float s  = v.x + v.y + v.z + v.w;
    float ss = v.x * v.x + v.y * v.y + v.z * v.z + v.w * v.w;
    for (int off = 1; off < 64; off <<= 1) {
        s  += __shfl_xor(s, off, 64);
        ss += __shfl_xor(ss, off, 64);
    }
    __shared__ float sm[8];
    const int wave = tid >> 6, lane = tid & 63;
    if (lane == 0) { sm[wave] = s; sm[4 + wave] = ss; }
    __syncthreads();
    s  = sm[0] + sm[1] + sm[2] + sm[3];
    ss = sm[4] + sm[5] + sm[6] + sm[7];
    const float mu  = s * (1.f / 1024.f);
    const float var = ss * (1.f / 1024.f) - mu * mu;
    const float inv = rsqrtf(var + 1e-5f);
    float* op = out + (size_t)row * 1024;
    const float* ve = &v.x;
    for (int j = 0; j < 4; j++) {
        const int c = tid * 4 + j;
        op[c] = (ve[j] - mu) * inv * gamma[c] + beta[c];
    }
}

// ---------------------------------------------------------------------------
extern "C" void kernel_launch(void* const* d_in, const int* in_sizes, int n_in,
                              void* d_out, int out_size, void* d_ws, size_t ws_size,
                              hipStream_t stream)
{
    const float* query     = (const float*)d_in[0];
    const float* key_value = (const float*)d_in[1];
    const float* relative  = (const float*)d_in[2];
    // d_in[3] = mask: analytic (j <= i+512), unused
    const float* Wq = (const float*)d_in[4];
    const float* Wk = (const float*)d_in[5];
    const float* Wv = (const float*)d_in[6];
    const float* Wr = (const float*)d_in[7];
    const float* Wo = (const float*)d_in[8];
    const float* u  = (const float*)d_in[9];
    const float* v  = (const float*)d_in[10];
    const float* gamma = (const float*)d_in[11];
    const float* beta  = (const float*)d_in[12];

    char* wsp = (char*)d_ws;
    auto alloc = [&](size_t bytes) -> char* {
        char* p = wsp; wsp += (bytes + 255) & ~(size_t)255; return p;
    };
    u16*   qb   = (u16*)alloc((size_t)4 * 1024 * 1024 * 2);      // bf16 query
    u16*   kvb  = (u16*)alloc((size_t)4 * 1536 * 1024 * 2);      // bf16 key_value
    u16*   relb = (u16*)alloc((size_t)4 * 1536 * 1024 * 2);      // bf16 relative
    u16*   WqT  = (u16*)alloc((size_t)1024 * 1024 * 2);
    u16*   WkrT = (u16*)alloc((size_t)1024 * 2048 * 2);
    u16*   WvT  = (u16*)alloc((size_t)1024 * 1024 * 2);
    u16*   WoT  = (u16*)alloc((size_t)1024 * 1024 * 2);
    u16*   wuvb = (u16*)alloc((size_t)16 * 2048 * 2);            // bf16 [16][2048]
    u16*   Qh   = (u16*)alloc((size_t)4 * 16 * 1024 * 64 * 2);
    u16*   KRh  = (u16*)alloc((size_t)4 * 16 * 1536 * 64 * 2);
    u16*   Vt   = (u16*)alloc((size_t)4 * 16 * 64 * 1536 * 2);   // transposed V
    float* bias = (float*)alloc((size_t)4 * 16 * 1536 * 4);
    u16*   ctx  = (u16*)alloc((size_t)4 * 1024 * 1024 * 2);
    float* outp = (float*)alloc((size_t)4 * 1024 * 1024 * 4);

    const dim3 tb(256);
    cvt_kernel<<<dim3(4 * 1024 * 1024 / 8 / 256), tb, 0, stream>>>(query, qb, 4 * 1024 * 1024);
    cvt_kernel<<<dim3(4 * 1536 * 1024 / 8 / 256), tb, 0, stream>>>(key_value, kvb, 4 * 1536 * 1024);
    cvt_kernel<<<dim3(4 * 1536 * 1024 / 8 / 256), tb, 0, stream>>>(relative, relb, 4 * 1536 * 1024);

    transpose_kernel<<<dim3(16, 16), tb, 0, stream>>>(Wq, WqT, 1024, 0);
    transpose_kernel<<<dim3(16, 16), tb, 0, stream>>>(Wk, WkrT, 2048, 0);
    transpose_kernel<<<dim3(16, 16), tb, 0, stream>>>(Wr, WkrT, 2048, 1024);
    transpose_kernel<<<dim3(16, 16), tb, 0, stream>>>(Wv, WvT, 1024, 0);
    transpose_kernel<<<dim3(16, 16), tb, 0, stream>>>(Wo, WoT, 1024, 0);
    wuv_kernel<<<64, tb, 0, stream>>>(Wk, Wr, u, v, wuvb);

    gemm_proj<0><<<dim3(32, 8), tb, 0, stream>>>(qb, nullptr, WqT, Qh, nullptr, 1024, 1024, 1024);
    gemm_proj<0><<<dim3(48, 8), tb, 0, stream>>>(kvb, relb, WkrT, KRh, nullptr, 2048, 1024, 1536);
    gemm_proj<2><<<dim3(48, 8), tb, 0, stream>>>(kvb, nullptr, WvT, Vt, nullptr, 1024, 1024, 1536);
    bias_kernel<<<dim3(96), tb, 0, stream>>>(kvb, relb, wuvb, bias);

    attn_kernel<<<dim3(512), tb, 0, stream>>>(Qh, KRh, Vt, bias, ctx);

    gemm_proj<1><<<dim3(32, 8), tb, 0, stream>>>(ctx, nullptr, WoT, outp, query, 1024, 1024, 1024);
    ln_kernel<<<4096, tb, 0, stream>>>(outp, gamma, beta, (float*)d_out);
}

// Round 7
// 345.322 us; speedup vs baseline: 1.4583x; 1.2541x over previous
//
#include <hip/hip_runtime.h>

// Transformer-XL attention, MI355X gfx950.
// All tensors fp32 in global (per reference); internal path bf16 MFMA + fp32 acc.
// B=4 TQ=1024 TK=1536 D=1024 H=16 DV=64, mem=512 causal: j <= i+512.
//
// Round-7 structure: projection GEMMs were 1-1.5 blocks/CU (1 wave/SIMD) as
// separate dispatches -> barrier/vmcnt drain fully exposed (round-6 postmortem:
// global_load_lds gained ~nothing at that occupancy). Fix = launch fusion:
// Q+KR+V+bias in ONE 1120-block dispatch; split-K=2 for the out GEMM.

typedef unsigned short u16;
typedef __attribute__((ext_vector_type(8))) short short8;   // 8 bf16 (MFMA A/B frag)
typedef __attribute__((ext_vector_type(4))) float floatx4;  // MFMA C/D frag

__device__ __forceinline__ float bf2f(u16 u) {
    union { unsigned int i; float f; } w; w.i = ((unsigned int)u) << 16; return w.f;
}
__device__ __forceinline__ u16 f2bf(float f) {
    union { unsigned int i; float f; } w; w.f = f;
    unsigned int u = w.i;
    return (u16)((u + 0x7FFFu + ((u >> 16) & 1u)) >> 16);
}

// async global->LDS, 16B per lane; LDS dest = wave-uniform base + lane*16
__device__ __forceinline__ void gl_lds16(const u16* g, u16* lds) {
    __builtin_amdgcn_global_load_lds(
        (const __attribute__((address_space(1))) void*)g,
        (__attribute__((address_space(3))) void*)lds, 16, 0, 0);
}

// ---------------------------------------------------------------------------
// Fused fp32 -> bf16 conversion for query/key_value/relative (grid.y selects)
// ---------------------------------------------------------------------------
__global__ __launch_bounds__(256) void cvt3_kernel(
    const float* __restrict__ x0, u16* __restrict__ y0, int n0,
    const float* __restrict__ x1, u16* __restrict__ y1, int n1,
    const float* __restrict__ x2, u16* __restrict__ y2, int n2)
{
    const int which = blockIdx.y;
    const float* x = (which == 0) ? x0 : (which == 1) ? x1 : x2;
    u16* y         = (which == 0) ? y0 : (which == 1) ? y1 : y2;
    const int n    = (which == 0) ? n0 : (which == 1) ? n1 : n2;
    const int i = (blockIdx.x * 256 + threadIdx.x) * 8;
    if (i >= n) return;
    float4 a = *(const float4*)&x[i];
    float4 b = *(const float4*)&x[i + 4];
    short8 o;
    o[0] = (short)f2bf(a.x); o[1] = (short)f2bf(a.y);
    o[2] = (short)f2bf(a.z); o[3] = (short)f2bf(a.w);
    o[4] = (short)f2bf(b.x); o[5] = (short)f2bf(b.y);
    o[6] = (short)f2bf(b.z); o[7] = (short)f2bf(b.w);
    *(short8*)&y[i] = o;
}

// ---------------------------------------------------------------------------
// Fused weight transpose + cvt: 5 weights in one dispatch (grid.z selects).
// WT[n][k] = bf16(W[k][n]); W is 1024x1024 fp32.
// ---------------------------------------------------------------------------
__global__ __launch_bounds__(256) void transpose5_kernel(
    const float* __restrict__ Wq, const float* __restrict__ Wk,
    const float* __restrict__ Wr, const float* __restrict__ Wv,
    const float* __restrict__ Wo,
    u16* __restrict__ WqT, u16* __restrict__ WkrT,
    u16* __restrict__ WvT, u16* __restrict__ WoT)
{
    const int z = blockIdx.z;
    const float* W; u16* WT; int dst_ld, dst_koff;
    switch (z) {
        case 0: W = Wq; WT = WqT;  dst_ld = 1024; dst_koff = 0;    break;
        case 1: W = Wk; WT = WkrT; dst_ld = 2048; dst_koff = 0;    break;
        case 2: W = Wr; WT = WkrT; dst_ld = 2048; dst_koff = 1024; break;
        case 3: W = Wv; WT = WvT;  dst_ld = 1024; dst_koff = 0;    break;
        default:W = Wo; WT = WoT;  dst_ld = 1024; dst_koff = 0;    break;
    }
    __shared__ u16 ts[64][72];
    const int k0 = blockIdx.x * 64, n0 = blockIdx.y * 64;
    const int r  = threadIdx.x >> 2;
    const int c4 = (threadIdx.x & 3) << 4;
    const float* src = &W[(size_t)(k0 + r) * 1024 + n0 + c4];
    for (int j = 0; j < 16; j += 4) {
        float4 a = *(const float4*)(src + j);
        ts[r][c4 + j + 0] = f2bf(a.x);
        ts[r][c4 + j + 1] = f2bf(a.y);
        ts[r][c4 + j + 2] = f2bf(a.z);
        ts[r][c4 + j + 3] = f2bf(a.w);
    }
    __syncthreads();
    short8 t0, t1;
    for (int j = 0; j < 8; j++) t0[j] = (short)ts[c4 + j][r];
    for (int j = 0; j < 8; j++) t1[j] = (short)ts[c4 + 8 + j][r];
    u16* dst = &WT[(size_t)(n0 + r) * dst_ld + dst_koff + k0 + c4];
    *(short8*)dst       = t0;
    *(short8*)(dst + 8) = t1;
}

// ---------------------------------------------------------------------------
// wuvb[h][k] (bf16, [16][2048]): k<1024 -> Wk[k][h*64+:]·u ; else Wr·v
// ---------------------------------------------------------------------------
__global__ __launch_bounds__(256) void wuv_kernel(
    const float* __restrict__ Wk, const float* __restrict__ Wr,
    const float* __restrict__ u, const float* __restrict__ v,
    u16* __restrict__ wuvb)
{
    int idx = blockIdx.x * 256 + threadIdx.x;
    int c = idx >> 4, h = idx & 15;
    float au = 0.f, av = 0.f;
    for (int d = 0; d < 64; d++) {
        au += Wk[(size_t)c * 1024 + h * 64 + d] * u[d];
        av += Wr[(size_t)c * 1024 + h * 64 + d] * v[d];
    }
    wuvb[h * 2048 + c]        = f2bf(au);
    wuvb[h * 2048 + 1024 + c] = f2bf(av);
}

// ---------------------------------------------------------------------------
// Shared 128x128 GEMM tile body (m97-style global_load_lds staging).
// EPI 0: bf16 head-layout out[((b*16+h)*T + t)*64 + d]
// EPI 2: bf16 head-transposed out[((b*16+h)*64 + d)*1536 + t]  (V^T)
// EPI 3: raw fp32 out[m*1024 + col]  (split-K partial)
// ---------------------------------------------------------------------------
template <int EPI>
__device__ __forceinline__ void gemm_body(
    const u16* __restrict__ A0, const u16* __restrict__ A1,
    const u16* __restrict__ WT, void* __restrict__ out,
    int Kld, int kbeg, int kend, int Ksplit, int T,
    int bm, int bn, u16* As, u16* Ws)
{
    const int tid = threadIdx.x;
    const int wave = tid >> 6, lane = tid & 63;
    const int wm = wave >> 1, wn = wave & 1;
    const int l16 = lane & 15, quad = lane >> 4;

    floatx4 acc[4][4];
    const floatx4 zf = {0.f, 0.f, 0.f, 0.f};
    for (int i = 0; i < 4; i++) for (int j = 0; j < 4; j++) acc[i][j] = zf;

    const int m_base = bm * 128, n_base = bn * 128;
    const int rl = lane >> 2;          // 0..15 row within 16-row DMA group
    const int cl = (lane & 3) * 8;     // 0,8,16,24 col elems (16B)

    for (int k0 = kbeg; k0 < kend; k0 += 32) {
        const u16* Aptr; int kk;
        if (k0 < Ksplit) { Aptr = A0; kk = k0; } else { Aptr = A1; kk = k0 - Ksplit; }
        __syncthreads();
        for (int half = 0; half < 2; half++) {
            const int r = wave * 32 + half * 16;  // wave-uniform LDS base row
            gl_lds16(Aptr + (size_t)(m_base + r + rl) * 1024 + kk + cl, &As[r * 32]);
            gl_lds16(WT   + (size_t)(n_base + r + rl) * Kld  + k0 + cl, &Ws[r * 32]);
        }
        __syncthreads();

        short8 af[4], bf[4];
        for (int i = 0; i < 4; i++) {
            af[i] = *(const short8*)&As[(wm * 64 + i * 16 + l16) * 32 + quad * 8];
            bf[i] = *(const short8*)&Ws[(wn * 64 + i * 16 + l16) * 32 + quad * 8];
        }
        for (int i = 0; i < 4; i++)
            for (int j = 0; j < 4; j++)
                acc[i][j] = __builtin_amdgcn_mfma_f32_16x16x32_bf16(af[i], bf[j], acc[i][j], 0, 0, 0);
    }

    for (int i = 0; i < 4; i++) {
        for (int rg = 0; rg < 4; rg++) {
            const int m = m_base + wm * 64 + i * 16 + quad * 4 + rg;
            if (EPI == 0) {
                const int b = m / T, t = m % T;
                u16* op = (u16*)out;
                for (int j = 0; j < 4; j++) {
                    const int col = n_base + wn * 64 + j * 16 + l16;
                    const int h = col >> 6, d = col & 63;
                    op[((((size_t)b * 16 + h) * T + t) << 6) + d] = f2bf(acc[i][j][rg]);
                }
            } else if (EPI == 2) {
                const int b = m / T, t = m % T;
                u16* op = (u16*)out;
                for (int j = 0; j < 4; j++) {
                    const int col = n_base + wn * 64 + j * 16 + l16;
                    const int h = col >> 6, d = col & 63;
                    op[(((size_t)b * 16 + h) * 64 + d) * 1536 + t] = f2bf(acc[i][j][rg]);
                }
            } else {
                float* op = (float*)out;
                for (int j = 0; j < 4; j++) {
                    const int col = n_base + wn * 64 + j * 16 + l16;
                    op[(size_t)m * 1024 + col] = acc[i][j][rg];
                }
            }
        }
    }
}

// ---------------------------------------------------------------------------
// bias body: [6144 tokens,2048]@[2048,16 heads] skinny MFMA, one wave/16 tokens
// ---------------------------------------------------------------------------
__device__ __forceinline__ void bias_body(
    const u16* __restrict__ kvb, const u16* __restrict__ relb,
    const u16* __restrict__ wuvb, float* __restrict__ bias, int bblk)
{
    const int tid = threadIdx.x;
    const int wave = tid >> 6, lane = tid & 63;
    const int l16 = lane & 15, quad = lane >> 4;
    const int tBase = bblk * 64 + wave * 16;

    floatx4 acc = {0.f, 0.f, 0.f, 0.f};
    const u16* arow_kv  = kvb  + (size_t)(tBase + l16) * 1024;
    const u16* arow_rel = relb + (size_t)(tBase + l16) * 1024;
    const u16* brow     = wuvb + (size_t)l16 * 2048;

    for (int ks = 0; ks < 64; ks++) {
        const int k0 = ks * 32;
        const u16* ap = (k0 < 1024) ? (arow_kv + k0) : (arow_rel + k0 - 1024);
        short8 af = *(const short8*)(ap + quad * 8);
        short8 bf = *(const short8*)(brow + k0 + quad * 8);
        acc = __builtin_amdgcn_mfma_f32_16x16x32_bf16(af, bf, acc, 0, 0, 0);
    }
    for (int rg = 0; rg < 4; rg++) {
        const int tg = tBase + quad * 4 + rg;
        const int b = tg / 1536, t = tg % 1536;
        bias[((size_t)b * 16 + l16) * 1536 + t] = acc[rg];
    }
}

// ---------------------------------------------------------------------------
// Fused projection dispatch: 1120 blocks (KR 384 | V 384 | Q 256 | bias 96).
// Longest-K (KR) first for tail balance. ~3-4 blocks/CU co-resident so
// barrier/vmcnt drains of one block overlap compute of others.
// ---------------------------------------------------------------------------
__global__ __launch_bounds__(256) void fused_proj(
    const u16* __restrict__ qb, const u16* __restrict__ kvb,
    const u16* __restrict__ relb,
    const u16* __restrict__ WqT, const u16* __restrict__ WkrT,
    const u16* __restrict__ WvT, const u16* __restrict__ wuvb,
    u16* __restrict__ Qh, u16* __restrict__ KRh, u16* __restrict__ Vt,
    float* __restrict__ bias)
{
    __shared__ u16 smem[2 * 128 * 32];
    u16* As = smem;
    u16* Ws = smem + 128 * 32;
    const int blk = blockIdx.x;
    if (blk < 384) {
        gemm_body<0>(kvb, relb, WkrT, KRh, 2048, 0, 2048, 1024, 1536,
                     blk % 48, blk / 48, As, Ws);
    } else if (blk < 768) {
        const int i = blk - 384;
        gemm_body<2>(kvb, nullptr, WvT, Vt, 1024, 0, 1024, 1024, 1536,
                     i % 48, i / 48, As, Ws);
    } else if (blk < 1024) {
        const int i = blk - 768;
        gemm_body<0>(qb, nullptr, WqT, Qh, 1024, 0, 1024, 1024, 1024,
                     i % 32, i / 32, As, Ws);
    } else {
        bias_body(kvb, relb, wuvb, bias, blk - 1024);
    }
}

// ---------------------------------------------------------------------------
// Output GEMM, split-K=2 (grid (32,8,2) = 512 blocks = 2/CU): raw fp32
// partials to outp + z*4M; LayerNorm sums partials + residual.
// ---------------------------------------------------------------------------
__global__ __launch_bounds__(256) void out_gemm(
    const u16* __restrict__ ctx, const u16* __restrict__ WoT,
    float* __restrict__ outp)
{
    __shared__ u16 smem[2 * 128 * 32];
    const int z = blockIdx.z;
    gemm_body<3>(ctx, nullptr, WoT,
                 outp + (size_t)z * 4 * 1024 * 1024, 1024,
                 z * 512, z * 512 + 512, 1024, 1024,
                 blockIdx.x, blockIdx.y, smem, smem + 128 * 32);
}

// ---------------------------------------------------------------------------
// Flash attention (round-4 tuning, 83.8 µs): 32 q/wave for load-ILP — round-5
// showed reg-capped TLP serializes the 16 staged b128 loads and loses 1.75x.
// No barriers; V pre-transposed; P via per-wave LDS; exact softmax, no max.
// 512 blocks: blk&63 = (b,h) XCD-residue swizzle.
// ---------------------------------------------------------------------------
__global__ __launch_bounds__(256) void attn_kernel(
    const u16* __restrict__ Qh,   // [B][H][1024][64]
    const u16* __restrict__ KRh,  // [B][H][1536][64]
    const u16* __restrict__ Vt,   // [B][H][64][1536]
    const float* __restrict__ bias, // [B][H][1536]
    u16* __restrict__ ctx)        // [B][1024][1024] token-major
{
    const int blk  = blockIdx.x;
    const int hb   = blk & 63;
    const int qblk = blk >> 6;
    const int b = hb >> 4, h = hb & 15;
    const int tid = threadIdx.x;
    const int wave = tid >> 6, lane = tid & 63;
    const int l16 = lane & 15, quad = lane >> 4;
    const int q0 = qblk * 128;

    const u16* Qp = Qh  + (size_t)hb * 1024 * 64;
    const u16* Kp = KRh + (size_t)hb * 1536 * 64;
    const u16* Vp = Vt  + (size_t)hb * 64 * 1536;
    const float* bp = bias + (size_t)hb * 1536;

    __shared__ u16 Ps[4][2][16][68];

    short8 aq[2][2];
    for (int mi = 0; mi < 2; mi++)
        for (int ks = 0; ks < 2; ks++)
            aq[mi][ks] = *(const short8*)
                &Qp[(size_t)(q0 + wave * 32 + mi * 16 + l16) * 64 + ks * 32 + quad * 8];

    const floatx4 zf = {0.f, 0.f, 0.f, 0.f};
    floatx4 accO[2][4];
    float lsum[2][4];
    for (int mi = 0; mi < 2; mi++)
        for (int j = 0; j < 4; j++) accO[mi][j] = zf;
    for (int mi = 0; mi < 2; mi++)
        for (int rg = 0; rg < 4; rg++) lsum[mi][rg] = 0.f;

    const int nkt = 2 * qblk + 10;
    for (int kt = 0; kt < nkt; kt++) {
        const int k0 = kt * 64;

        short8 bk[4][2], bv[4][2];
        float bcol[4];
        for (int n = 0; n < 4; n++)
            for (int ks = 0; ks < 2; ks++)
                bk[n][ks] = *(const short8*)
                    &Kp[(size_t)(k0 + n * 16 + l16) * 64 + ks * 32 + quad * 8];
        for (int j = 0; j < 4; j++)
            for (int ks = 0; ks < 2; ks++)
                bv[j][ks] = *(const short8*)
                    &Vp[(size_t)(j * 16 + l16) * 1536 + k0 + ks * 32 + quad * 8];
        for (int n = 0; n < 4; n++) bcol[n] = bp[k0 + n * 16 + l16];

        const bool domask = (k0 + 63 > q0 + 512);

        for (int mi = 0; mi < 2; mi++) {
            floatx4 accS[4];
            for (int n = 0; n < 4; n++) {
                accS[n] = zf;
                for (int ks = 0; ks < 2; ks++)
                    accS[n] = __builtin_amdgcn_mfma_f32_16x16x32_bf16(
                        aq[mi][ks], bk[n][ks], accS[n], 0, 0, 0);
            }
            const int qrow = q0 + wave * 32 + mi * 16 + quad * 4;
            for (int n = 0; n < 4; n++) {
                const int col = k0 + n * 16 + l16;
                for (int rg = 0; rg < 4; rg++) {
                    float s = (accS[n][rg] + bcol[n]) * 0.125f;
                    if (domask && col > qrow + rg + 512) s = -1e30f;
                    const float p = __expf(s);
                    lsum[mi][rg] += p;
                    Ps[wave][mi][quad * 4 + rg][n * 16 + l16] = f2bf(p);
                }
            }
            short8 ap[2];
            for (int ks = 0; ks < 2; ks++)
                ap[ks] = *(const short8*)&Ps[wave][mi][l16][ks * 32 + quad * 8];
            for (int j = 0; j < 4; j++)
                for (int ks = 0; ks < 2; ks++)
                    accO[mi][j] = __builtin_amdgcn_mfma_f32_16x16x32_bf16(
                        ap[ks], bv[j][ks], accO[mi][j], 0, 0, 0);
        }
    }

    for (int mi = 0; mi < 2; mi++)
        for (int rg = 0; rg < 4; rg++) {
            float s = lsum[mi][rg];
            for (int off = 1; off < 16; off <<= 1) s += __shfl_xor(s, off, 64);
            lsum[mi][rg] = s;
        }

    for (int mi = 0; mi < 2; mi++)
        for (int j = 0; j < 4; j++)
            for (int rg = 0; rg < 4; rg++) {
                const int q = q0 + wave * 32 + mi * 16 + quad * 4 + rg;
                const int d = j * 16 + l16;
                ctx[((size_t)b * 1024 + q) * 1024 + h * 64 + d] =
                    f2bf(accO[mi][j][rg] / lsum[mi][rg]);
            }
}

// ---------------------------------------------------------------------------
// LayerNorm over (partial0 + partial1 + residual query): fp32 -> fp32 d_out
// ---------------------------------------------------------------------------
__global__ __launch_bounds__(256) void ln_kernel(
    const float* __restrict__ x0, const float* __restrict__ x1,
    const float* __restrict__ q,
    const float* __restrict__ gamma, const float* __restrict__ beta,
    float* __restrict__ out)
{
    const int row = blockIdx.x;
    const int tid = threadIdx.x;
    const size_t base = (size_t)row * 1024 + tid * 4;
    float4 a = *(const float4*)&x0[base];
    float4 c = *(const float4*)&x1[base];
    float4 r = *(const float4*)&q[base];
    float4 v;
    v.x = a.x + c.x + r.x; v.y = a.y + c.y + r.y;
    v.z = a.z + c.z + r.z; v.w = a.w + c.w + r.w;
    float s  = v.x + v.y + v.z + v.w;
    float ss = v.x * v.x + v.y * v.y + v.z * v.z + v.w * v.w;
    for (int off = 1; off < 64; off <<= 1) {
        s  += __shfl_xor(s, off, 64);
        ss += __shfl_xor(ss, off, 64);
    }
    __shared__ float sm[8];
    const int wave = tid >> 6, lane = tid & 63;
    if (lane == 0) { sm[wave] = s; sm[4 + wave] = ss; }
    __syncthreads();
    s  = sm[0] + sm[1] + sm[2] + sm[3];
    ss = sm[4] + sm[5] + sm[6] + sm[7];
    const float mu  = s * (1.f / 1024.f);
    const float var = ss * (1.f / 1024.f) - mu * mu;
    const float inv = rsqrtf(var + 1e-5f);
    float* op = out + (size_t)row * 1024;
    const float* ve = &v.x;
    for (int j = 0; j < 4; j++) {
        const int c2 = tid * 4 + j;
        op[c2] = (ve[j] - mu) * inv * gamma[c2] + beta[c2];
    }
}

// ---------------------------------------------------------------------------
extern "C" void kernel_launch(void* const* d_in, const int* in_sizes, int n_in,
                              void* d_out, int out_size, void* d_ws, size_t ws_size,
                              hipStream_t stream)
{
    const float* query     = (const float*)d_in[0];
    const float* key_value = (const float*)d_in[1];
    const float* relative  = (const float*)d_in[2];
    // d_in[3] = mask: analytic (j <= i+512), unused
    const float* Wq = (const float*)d_in[4];
    const float* Wk = (const float*)d_in[5];
    const float* Wv = (const float*)d_in[6];
    const float* Wr = (const float*)d_in[7];
    const float* Wo = (const float*)d_in[8];
    const float* u  = (const float*)d_in[9];
    const float* v  = (const float*)d_in[10];
    const float* gamma = (const float*)d_in[11];
    const float* beta  = (const float*)d_in[12];

    char* wsp = (char*)d_ws;
    auto alloc = [&](size_t bytes) -> char* {
        char* p = wsp; wsp += (bytes + 255) & ~(size_t)255; return p;
    };
    u16*   qb   = (u16*)alloc((size_t)4 * 1024 * 1024 * 2);
    u16*   kvb  = (u16*)alloc((size_t)4 * 1536 * 1024 * 2);
    u16*   relb = (u16*)alloc((size_t)4 * 1536 * 1024 * 2);
    u16*   WqT  = (u16*)alloc((size_t)1024 * 1024 * 2);
    u16*   WkrT = (u16*)alloc((size_t)1024 * 2048 * 2);
    u16*   WvT  = (u16*)alloc((size_t)1024 * 1024 * 2);
    u16*   WoT  = (u16*)alloc((size_t)1024 * 1024 * 2);
    u16*   wuvb = (u16*)alloc((size_t)16 * 2048 * 2);
    u16*   Qh   = (u16*)alloc((size_t)4 * 16 * 1024 * 64 * 2);
    u16*   KRh  = (u16*)alloc((size_t)4 * 16 * 1536 * 64 * 2);
    u16*   Vt   = (u16*)alloc((size_t)4 * 16 * 64 * 1536 * 2);
    float* bias = (float*)alloc((size_t)4 * 16 * 1536 * 4);
    u16*   ctx  = (u16*)alloc((size_t)4 * 1024 * 1024 * 2);
    float* outp = (float*)alloc((size_t)2 * 4 * 1024 * 1024 * 4);  // 2 split-K partials

    const dim3 tb(256);
    cvt3_kernel<<<dim3(3072, 3), tb, 0, stream>>>(
        query, qb, 4 * 1024 * 1024,
        key_value, kvb, 4 * 1536 * 1024,
        relative, relb, 4 * 1536 * 1024);

    transpose5_kernel<<<dim3(16, 16, 5), tb, 0, stream>>>(
        Wq, Wk, Wr, Wv, Wo, WqT, WkrT, WvT, WoT);
    wuv_kernel<<<64, tb, 0, stream>>>(Wk, Wr, u, v, wuvb);

    fused_proj<<<dim3(1120), tb, 0, stream>>>(
        qb, kvb, relb, WqT, WkrT, WvT, wuvb, Qh, KRh, Vt, bias);

    attn_kernel<<<dim3(512), tb, 0, stream>>>(Qh, KRh, Vt, bias, ctx);

    out_gemm<<<dim3(32, 8, 2), tb, 0, stream>>>(ctx, WoT, outp);
    ln_kernel<<<4096, tb, 0, stream>>>(
        outp, outp + (size_t)4 * 1024 * 1024, query, gamma, beta, (float*)d_out);
}